// Round 4
// baseline (2072.451 us; speedup 1.0000x reference)
//
#include <hip/hip_runtime.h>
#include <math.h>

// MAGNO decoder, MI355X — round 4: spill fix + parallel top-k extraction.
//   B=2, NL=2048, NQ=16384, CD=2, CIN=H=64, PH=256, COUT=3, K=32, scales {1,2}.
//
// Round-3 post-mortem: WRITE_SIZE 2.07 GB = partial scratch spill of acc[]
// (VGPR_Count 88 < ~105 needed); VALUBusy 34%. Round-4 changes:
//  * __attribute__((amdgpu_waves_per_eu(1))): min-occupancy 1 wave/EU ->
//    512-VGPR ceiling, allocator must not spill ~105 live regs.
//  * i-loop unroll 4 -> 2: halves in-flight s_load weight values (SGPR=112
//    was at/near the scalar budget -> scalar spill pressure).
//  * Phase-1 top-32 extraction now runs BOTH queries concurrently, one per
//    half-wave (butterfly confined to 32 lanes); candidate buffers overlaid
//    into `big` (phase-disjoint) -> CAP 512 and LDS 19.9 -> 17.7 KB
//    (9 blocks/CU instead of 8).
// Unchanged (verified round 3): lane=edge phase 2 with SGPR weight streaming,
// d2 via __fmul_rn/__fadd_rn (bit-exact radius/top-k boundaries), stride-65
// LDS transpose reduce, fused projection.

#define NLAT 2048
#define NQ_TOT 32768   // B * NQ
#define KNB 32
#define CAP 512        // per-query candidate cap (overlaid in `big`)

__device__ __forceinline__ float gelu_exact(float x) {
  // jax.nn.gelu(approximate=False): 0.5*x*(1+erf(x/sqrt(2)))
  return 0.5f * x * (1.0f + erff(x * 0.70710678118654752440f));
}

__global__ __launch_bounds__(64) __attribute__((amdgpu_waves_per_eu(1)))
void magno_fused(const float* __restrict__ lat,   // [NL,2]
                 const float* __restrict__ rn,    // [B,NL,64]
                 const float* __restrict__ qc,    // [B*NQ,2]
                 const float* __restrict__ w_e0, const float* __restrict__ b_e0,
                 const float* __restrict__ w_e1, const float* __restrict__ b_e1,
                 const float* __restrict__ w_e2, const float* __restrict__ b_e2,
                 const float* __restrict__ w_sw0, const float* __restrict__ b_sw0,
                 const float* __restrict__ w_sw1, const float* __restrict__ b_sw1,
                 const float* __restrict__ w_p0, const float* __restrict__ b_p0,
                 const float* __restrict__ w_p1, const float* __restrict__ b_p1,
                 float* __restrict__ out)         // [B*NQ,3]
{
  const float r1sq = (float)(0.055 * 0.055);
  const float r2sq = (float)((0.055 * 2.0) * (0.055 * 2.0));

  // big: phase 1 = candidate buffers [cd2 q0 | cidx q0 | cd2 q1 | cidx q1]
  //      phase 2 = h1[ch][lane] (stride 64); phase 4 = contrib (stride 65)
  __shared__ float big[64 * 65];                  // 4160 floats = 16.6 KB
  __shared__ float sd2[2][KNB];
  __shared__ int   sidx[2][KNB];
  __shared__ float dec_lds[2][64];

  const int lane = threadIdx.x;
  const int sub  = lane >> 5;                     // wave's query 0/1
  const int e32  = lane & 31;                     // edge slot / half-lane

  // ==== phase 1a: distance pass + compaction (full wave, per query) ========
  int nc0 = 0, nc1 = 0;
#pragma unroll
  for (int s = 0; s < 2; ++s) {
    float* cds = big + s * 2 * CAP;
    int*   cis = (int*)(big + CAP + s * 2 * CAP);
    const int gq = blockIdx.x * 2 + s;
    const float2 qv = *(const float2*)&qc[2 * gq];
    int nc = 0;
    for (int t = 0; t < NLAT; t += 64) {
      const int l = t + lane;
      const float2 yv = *(const float2*)&lat[2 * l];
      const float dx = qv.x - yv.x, dy = qv.y - yv.y;
      const float d2 = __fadd_rn(__fmul_rn(dx, dx), __fmul_rn(dy, dy));
      const bool hit = d2 <= r2sq;
      const unsigned long long m = __ballot(hit);
      if (hit) {
        const int pos = nc + __popcll(m & (((unsigned long long)1 << lane) - 1ull));
        if (pos < CAP) { cds[pos] = d2; cis[pos] = l; }
      }
      nc += (int)__popcll(m);
    }
    if (nc > CAP) nc = CAP;    // ~30 sigma above the mean of ~78; unreachable
    if (s == 0) nc0 = nc; else nc1 = nc;
  }
  __syncthreads();

  // ==== phase 1b: top-32 by (d2,pos), both queries in parallel =============
  const int ncH = sub ? nc1 : nc0;
  float* cdH = big + sub * 2 * CAP;
  int*   ciH = (int*)(big + CAP + sub * 2 * CAP);

  if (ncH <= KNB) {                               // all candidates selected
    if (e32 < ncH) { sd2[sub][e32] = cdH[e32]; sidx[sub][e32] = ciH[e32]; }
  }
  __syncthreads();
  if (nc0 > KNB || nc1 > KNB) {                   // wave-uniform condition
    const bool ext = ncH > KNB;
    for (int r = 0; r < KNB; ++r) {
      unsigned long long best = ~0ull;
      if (ext) {
        for (int t = e32; t < ncH; t += 32) {
          const unsigned long long key =
              ((unsigned long long)__float_as_uint(cdH[t]) << 32) | (unsigned)t;
          if (key < best) best = key;
        }
      }
#pragma unroll
      for (int off = 16; off > 0; off >>= 1) {    // butterfly within half-wave
        const unsigned long long o = __shfl_xor(best, off);
        if (o < best) best = o;
      }
      if (ext && e32 == 0) {
        const int pos = (int)(best & 0xffffffffu);
        sd2[sub][r]  = __uint_as_float((unsigned)(best >> 32));
        sidx[sub][r] = ciH[pos];
        cdH[pos] = __uint_as_float(0x7f800000u);  // +inf: claimed
      }
      __syncthreads();
    }
  }
  const int n_sel = ncH < KNB ? ncH : KNB;

  // ==== phase 2: lane = edge; edge MLP with SGPR-streamed weights ==========
  const int gq = blockIdx.x * 2 + sub;
  const int bb = gq >> 14;                        // batch = gq / NQ
  const float2 qv = *(const float2*)&qc[2 * gq];

  const bool  active = e32 < n_sel;
  const float d2e = active ? sd2[sub][e32] : 1e30f;
  const int   ie  = active ? sidx[sub][e32] : 0;
  const float2 yv = *(const float2*)&lat[2 * ie];
  __syncthreads();                                // cand reads done; reuse big

  // layer 0: h1 -> LDS (lane-major; conflict-free)
#pragma unroll 2
  for (int i = 0; i < 64; ++i) {
    const float t = fmaf(yv.x, w_e0[i],
                    fmaf(yv.y, w_e0[64 + i],
                    fmaf(qv.x, w_e0[128 + i],
                    fmaf(qv.y, w_e0[192 + i], b_e0[i]))));
    big[i * 64 + lane] = gelu_exact(t);
  }
  __syncthreads();

  // layers 1+2 fused: 8 groups of 8 hidden channels; weights via s_load
  float acc[64];
#pragma unroll
  for (int j = 0; j < 64; ++j) acc[j] = b_e2[j];

  for (int g = 0; g < 8; ++g) {
    float L[8];
#pragma unroll
    for (int k = 0; k < 8; ++k) L[k] = b_e1[g * 8 + k];
#pragma unroll 2
    for (int i = 0; i < 64; ++i) {
      const float hi = big[i * 64 + lane];
      const float* wr = &w_e1[i * 64 + g * 8];
      L[0] = fmaf(hi, wr[0], L[0]); L[1] = fmaf(hi, wr[1], L[1]);
      L[2] = fmaf(hi, wr[2], L[2]); L[3] = fmaf(hi, wr[3], L[3]);
      L[4] = fmaf(hi, wr[4], L[4]); L[5] = fmaf(hi, wr[5], L[5]);
      L[6] = fmaf(hi, wr[6], L[6]); L[7] = fmaf(hi, wr[7], L[7]);
    }
#pragma unroll
    for (int k = 0; k < 8; ++k) {
      const float hk = gelu_exact(L[k]);
      const float* w2r = &w_e2[(g * 8 + k) * 64];
#pragma unroll
      for (int jj = 0; jj < 64; ++jj) acc[jj] = fmaf(hk, w2r[jj], acc[jj]);
    }
  }

  // ==== phase 3: scale-mix softmax + per-edge factor ========================
  float z0 = b_sw1[0], z1 = b_sw1[1];
#pragma unroll
  for (int k = 0; k < 16; ++k) {
    float t = fmaf(qv.x, w_sw0[k], fmaf(qv.y, w_sw0[16 + k], b_sw0[k]));
    t = fmaxf(t, 0.f);
    z0 = fmaf(t, w_sw1[2 * k + 0], z0);
    z1 = fmaf(t, w_sw1[2 * k + 1], z1);
  }
  const float mz = fmaxf(z0, z1);
  const float ex0 = expf(z0 - mz), ex1 = expf(z1 - mz);
  const float inv = 1.f / (ex0 + ex1);
  const float sw0 = ex0 * inv, sw1 = ex1 * inv;   // sw0<->scale1, sw1<->scale2

  const bool v1 = active && (d2e <= r1sq);
  const unsigned long long mB = __ballot(v1);
  const int cnt1 = (int)__popcll((mB >> (lane & 32)) & 0xffffffffull);
  float fac = 0.f;
  if (active) {
    fac = sw1 / (float)n_sel;                     // n_sel >= 1 when active
    if (v1) fac += sw0 / (float)cnt1;             // cnt1 >= 1 when v1
  }

  // ==== phase 4: contrib -> LDS (stride 65), transpose-reduce over edges ====
  __syncthreads();                                // h1 reads done; reuse big
  const float* rnp = rn + ((size_t)bb * NLAT + ie) * 64;
#pragma unroll 4
  for (int jj = 0; jj < 64; jj += 4) {
    const float4 r4 = *(const float4*)&rnp[jj];
    float* row = &big[lane * 65];
    row[jj + 0] = acc[jj + 0] * r4.x * fac;
    row[jj + 1] = acc[jj + 1] * r4.y * fac;
    row[jj + 2] = acc[jj + 2] * r4.z * fac;
    row[jj + 3] = acc[jj + 3] * r4.w * fac;
  }
  __syncthreads();
  {
    const int qh = lane >> 5;                     // query this lane reduces
    const int j0 = (lane & 31) * 2;               // its 2 channels
    float s0 = 0.f, s1 = 0.f;
#pragma unroll 4
    for (int ee = 0; ee < 32; ++ee) {
      const float* row = &big[(qh * 32 + ee) * 65];
      s0 += row[j0];
      s1 += row[j0 + 1];
    }
    dec_lds[qh][j0]     = s0;
    dec_lds[qh][j0 + 1] = s1;
  }
  __syncthreads();

  // ==== phase 5: fused projection MLP ======================================
  // lane owns PH channels e32*8 .. e32*8+7 of its query's hidden vector
  float ph[8];
  {
    const float4 ba = *(const float4*)&b_p0[e32 * 8];
    const float4 bc = *(const float4*)&b_p0[e32 * 8 + 4];
    ph[0] = ba.x; ph[1] = ba.y; ph[2] = ba.z; ph[3] = ba.w;
    ph[4] = bc.x; ph[5] = bc.y; ph[6] = bc.z; ph[7] = bc.w;
  }
#pragma unroll 2
  for (int i = 0; i < 64; ++i) {
    const float di = dec_lds[sub][i];             // LDS broadcast per half
    const float4 wa = *(const float4*)&w_p0[i * 256 + e32 * 8];
    const float4 wb = *(const float4*)&w_p0[i * 256 + e32 * 8 + 4];
    ph[0] = fmaf(di, wa.x, ph[0]); ph[1] = fmaf(di, wa.y, ph[1]);
    ph[2] = fmaf(di, wa.z, ph[2]); ph[3] = fmaf(di, wa.w, ph[3]);
    ph[4] = fmaf(di, wb.x, ph[4]); ph[5] = fmaf(di, wb.y, ph[5]);
    ph[6] = fmaf(di, wb.z, ph[6]); ph[7] = fmaf(di, wb.w, ph[7]);
  }

  float o0 = 0.f, o1 = 0.f, o2 = 0.f;
#pragma unroll
  for (int k = 0; k < 8; ++k) {
    const float gk = gelu_exact(ph[k]);
    const int row = e32 * 8 + k;
    o0 = fmaf(gk, w_p1[row * 3 + 0], o0);
    o1 = fmaf(gk, w_p1[row * 3 + 1], o1);
    o2 = fmaf(gk, w_p1[row * 3 + 2], o2);
  }
#pragma unroll
  for (int off = 1; off < 32; off <<= 1) {
    o0 += __shfl_xor(o0, off);
    o1 += __shfl_xor(o1, off);
    o2 += __shfl_xor(o2, off);
  }
  if (e32 == 0) {
    out[(size_t)gq * 3 + 0] = o0 + b_p1[0];
    out[(size_t)gq * 3 + 1] = o1 + b_p1[1];
    out[(size_t)gq * 3 + 2] = o2 + b_p1[2];
  }
}

extern "C" void kernel_launch(void* const* d_in, const int* in_sizes, int n_in,
                              void* d_out, int out_size, void* d_ws, size_t ws_size,
                              hipStream_t stream) {
  const float* lat   = (const float*)d_in[0];
  const float* rn    = (const float*)d_in[1];
  const float* qc    = (const float*)d_in[2];
  const float* w_e0  = (const float*)d_in[3];
  const float* b_e0  = (const float*)d_in[4];
  const float* w_e1  = (const float*)d_in[5];
  const float* b_e1  = (const float*)d_in[6];
  const float* w_e2  = (const float*)d_in[7];
  const float* b_e2  = (const float*)d_in[8];
  const float* w_sw0 = (const float*)d_in[9];
  const float* b_sw0 = (const float*)d_in[10];
  const float* w_sw1 = (const float*)d_in[11];
  const float* b_sw1 = (const float*)d_in[12];
  const float* w_p0  = (const float*)d_in[13];
  const float* b_p0  = (const float*)d_in[14];
  const float* w_p1  = (const float*)d_in[15];
  const float* b_p1  = (const float*)d_in[16];

  float* out = (float*)d_out;

  hipLaunchKernelGGL(magno_fused, dim3(NQ_TOT / 2), dim3(64), 0, stream,
                     lat, rn, qc, w_e0, b_e0, w_e1, b_e1, w_e2, b_e2,
                     w_sw0, b_sw0, w_sw1, b_sw1, w_p0, b_p0, w_p1, b_p1, out);
}

// Round 5
// 1455.390 us; speedup vs baseline: 1.4240x; 1.4240x over previous
//
#include <hip/hip_runtime.h>
#include <math.h>

// MAGNO decoder, MI355X — round 5: bounded-register restructure.
//   B=2, NL=2048, NQ=16384, CD=2, CIN=H=64, PH=256, COUT=3, K=32, scales {1,2}.
//
// Round-3/4 post-mortem: acc[64] per-lane accumulator spilled (WRITE_SIZE
// 2-3.4 GB of scratch; VGPR_Count 88/68 < demand ~105). The allocator's
// occupancy heuristic won't grant ~105 regs, so this round removes the
// demand instead of fighting the heuristic:
//  * h1[64] in REGISTERS (read-only, fully-unrolled static indexing).
//  * h2 -> LDS [64 k][64 lane], produced 8-at-a-time (only L[8] live).
//  * layer 2 chunked: 4 x acc[16]; each chunk finalized (x rn x fac) into a
//    64x17 LDS transpose buffer and edge-reduced immediately -> no wide
//    accumulator ever lives in registers. Peak live ~84 VGPR (layer 1).
//  * candidates overlay the h2 buffer (phase-disjoint); LDS ~21.5 KB ->
//    7 blocks/CU (~1.75 waves/SIMD).
// Unchanged verified machinery: lane=edge, wave-uniform weight s_load
// streaming, d2 via __fmul_rn/__fadd_rn (bit-exact radius/top-k decisions),
// (d2,pos) lexicographic top-32 == jax.lax.top_k stable set, fused
// projection MLP.

#define NLAT 2048
#define NQ_TOT 32768   // B * NQ
#define KNB 32
#define CAP 512        // per-query candidate cap (overlaid in `big`)

__device__ __forceinline__ float gelu_exact(float x) {
  // jax.nn.gelu(approximate=False): 0.5*x*(1+erf(x/sqrt(2)))
  return 0.5f * x * (1.0f + erff(x * 0.70710678118654752440f));
}

__global__ __launch_bounds__(64, 2) __attribute__((amdgpu_waves_per_eu(2, 4)))
void magno_fused(const float* __restrict__ lat,   // [NL,2]
                 const float* __restrict__ rn,    // [B,NL,64]
                 const float* __restrict__ qc,    // [B*NQ,2]
                 const float* __restrict__ w_e0, const float* __restrict__ b_e0,
                 const float* __restrict__ w_e1, const float* __restrict__ b_e1,
                 const float* __restrict__ w_e2, const float* __restrict__ b_e2,
                 const float* __restrict__ w_sw0, const float* __restrict__ b_sw0,
                 const float* __restrict__ w_sw1, const float* __restrict__ b_sw1,
                 const float* __restrict__ w_p0, const float* __restrict__ b_p0,
                 const float* __restrict__ w_p1, const float* __restrict__ b_p1,
                 float* __restrict__ out)         // [B*NQ,3]
{
  const float r1sq = (float)(0.055 * 0.055);
  const float r2sq = (float)((0.055 * 2.0) * (0.055 * 2.0));

  // big: phase 1 = candidates [cd2 q0 | cidx q0 | cd2 q1 | cidx q1] (4*512)
  //      phase 2 = h2[64 k][64 lane]
  __shared__ float big[4096];                     // 16 KB
  __shared__ float cbuf[64 * 17];                 // chunk contrib transpose, 4.25 KB
  __shared__ float sd2[2][KNB];
  __shared__ int   sidx[2][KNB];
  __shared__ float dec_lds[2][64];

  const int lane = threadIdx.x;
  const int sub  = lane >> 5;                     // wave's query 0/1
  const int e32  = lane & 31;                     // edge slot within query

  // ==== phase 1a: distance pass + compaction (full wave, per query) ========
  int nc0 = 0, nc1 = 0;
#pragma unroll
  for (int s = 0; s < 2; ++s) {
    float* cds = big + s * 2 * CAP;
    int*   cis = (int*)(big + CAP + s * 2 * CAP);
    const int gqs = blockIdx.x * 2 + s;
    const float2 qs = *(const float2*)&qc[2 * gqs];
    int nc = 0;
    for (int t = 0; t < NLAT; t += 64) {
      const int l = t + lane;
      const float2 yv = *(const float2*)&lat[2 * l];
      const float dx = qs.x - yv.x, dy = qs.y - yv.y;
      const float d2 = __fadd_rn(__fmul_rn(dx, dx), __fmul_rn(dy, dy));
      const bool hit = d2 <= r2sq;
      const unsigned long long m = __ballot(hit);
      if (hit) {
        const int pos = nc + __popcll(m & (((unsigned long long)1 << lane) - 1ull));
        if (pos < CAP) { cds[pos] = d2; cis[pos] = l; }
      }
      nc += (int)__popcll(m);
    }
    if (nc > CAP) nc = CAP;    // mean ~78; unreachable
    if (s == 0) nc0 = nc; else nc1 = nc;
  }
  __syncthreads();

  // ==== phase 1b: top-32 by (d2,pos), both queries in half-wave parallel ===
  const int ncH = sub ? nc1 : nc0;
  float* cdH = big + sub * 2 * CAP;
  int*   ciH = (int*)(big + CAP + sub * 2 * CAP);

  if (ncH <= KNB) {
    if (e32 < ncH) { sd2[sub][e32] = cdH[e32]; sidx[sub][e32] = ciH[e32]; }
  }
  __syncthreads();
  if (nc0 > KNB || nc1 > KNB) {                   // wave-uniform condition
    const bool ext = ncH > KNB;
    for (int r = 0; r < KNB; ++r) {
      unsigned long long best = ~0ull;
      if (ext) {
        for (int t = e32; t < ncH; t += 32) {
          const unsigned long long key =
              ((unsigned long long)__float_as_uint(cdH[t]) << 32) | (unsigned)t;
          if (key < best) best = key;
        }
      }
#pragma unroll
      for (int off = 16; off > 0; off >>= 1) {    // butterfly within half-wave
        const unsigned long long o = __shfl_xor(best, off);
        if (o < best) best = o;
      }
      if (ext && e32 == 0) {
        const int pos = (int)(best & 0xffffffffu);
        sd2[sub][r]  = __uint_as_float((unsigned)(best >> 32));
        sidx[sub][r] = ciH[pos];
        cdH[pos] = __uint_as_float(0x7f800000u);  // +inf: claimed
      }
      __syncthreads();
    }
  }
  const int n_sel = ncH < KNB ? ncH : KNB;

  // ==== phase 2: lane = edge ===============================================
  const int gq = blockIdx.x * 2 + sub;
  const int bb = gq >> 14;                        // batch = gq / NQ
  const float2 qv = *(const float2*)&qc[2 * gq];

  const bool  active = e32 < n_sel;
  const float d2e = active ? sd2[sub][e32] : 1e30f;
  const int   ie  = active ? sidx[sub][e32] : 0;
  const float2 yv = *(const float2*)&lat[2 * ie];
  __syncthreads();                                // candidate reads done

  // layer 0: h1 in registers (static indices; weights via s_load)
  float h1[64];
#pragma unroll
  for (int i = 0; i < 64; ++i) {
    const float t = fmaf(yv.x, w_e0[i],
                    fmaf(yv.y, w_e0[64 + i],
                    fmaf(qv.x, w_e0[128 + i],
                    fmaf(qv.y, w_e0[192 + i], b_e0[i]))));
    h1[i] = gelu_exact(t);
  }

  // layer 1: 8 groups of 8; only L[8] live; h2 -> LDS `big`
  for (int g = 0; g < 8; ++g) {
    float L[8];
#pragma unroll
    for (int k = 0; k < 8; ++k) L[k] = b_e1[g * 8 + k];
#pragma unroll
    for (int i = 0; i < 64; ++i) {
      const float hi = h1[i];
      const float* wr = &w_e1[i * 64 + g * 8];
      L[0] = fmaf(hi, wr[0], L[0]); L[1] = fmaf(hi, wr[1], L[1]);
      L[2] = fmaf(hi, wr[2], L[2]); L[3] = fmaf(hi, wr[3], L[3]);
      L[4] = fmaf(hi, wr[4], L[4]); L[5] = fmaf(hi, wr[5], L[5]);
      L[6] = fmaf(hi, wr[6], L[6]); L[7] = fmaf(hi, wr[7], L[7]);
    }
#pragma unroll
    for (int k = 0; k < 8; ++k) big[(g * 8 + k) * 64 + lane] = gelu_exact(L[k]);
  }

  // scale-mix softmax + per-edge factor (before layer 2; h1 now dead)
  float z0 = b_sw1[0], z1 = b_sw1[1];
#pragma unroll
  for (int k = 0; k < 16; ++k) {
    float t = fmaf(qv.x, w_sw0[k], fmaf(qv.y, w_sw0[16 + k], b_sw0[k]));
    t = fmaxf(t, 0.f);
    z0 = fmaf(t, w_sw1[2 * k + 0], z0);
    z1 = fmaf(t, w_sw1[2 * k + 1], z1);
  }
  const float mz = fmaxf(z0, z1);
  const float ex0 = expf(z0 - mz), ex1 = expf(z1 - mz);
  const float inv = 1.f / (ex0 + ex1);
  const float sw0 = ex0 * inv, sw1 = ex1 * inv;   // sw0<->scale1, sw1<->scale2

  const bool v1 = active && (d2e <= r1sq);
  const unsigned long long mB = __ballot(v1);
  const int cnt1 = (int)__popcll((mB >> (lane & 32)) & 0xffffffffull);
  float fac = 0.f;
  if (active) {
    fac = sw1 / (float)n_sel;
    if (v1) fac += sw0 / (float)cnt1;
  }

  __syncthreads();                                // h2 fully written

  // layer 2: 4 chunks of 16 output channels; per-chunk finalize + edge-reduce
  const float* rnp = rn + ((size_t)bb * NLAT + ie) * 64;
  const int p   = lane >> 1;                      // reduce pair id 0..31
  const int qh  = p >> 4;                         // query reduced by this lane
  const int cc  = p & 15;                         // channel-in-chunk
  const int er0 = (lane & 1) * 16;                // edge sub-range base

  for (int c = 0; c < 4; ++c) {
    float acc[16];
#pragma unroll
    for (int k = 0; k < 16; ++k) acc[k] = b_e2[c * 16 + k];
#pragma unroll
    for (int k = 0; k < 64; ++k) {
      const float hk = big[k * 64 + lane];        // ds_read, imm offset
      const float* w2r = &w_e2[k * 64 + c * 16];  // wave-uniform -> s_load
      acc[0]  = fmaf(hk, w2r[0],  acc[0]);  acc[1]  = fmaf(hk, w2r[1],  acc[1]);
      acc[2]  = fmaf(hk, w2r[2],  acc[2]);  acc[3]  = fmaf(hk, w2r[3],  acc[3]);
      acc[4]  = fmaf(hk, w2r[4],  acc[4]);  acc[5]  = fmaf(hk, w2r[5],  acc[5]);
      acc[6]  = fmaf(hk, w2r[6],  acc[6]);  acc[7]  = fmaf(hk, w2r[7],  acc[7]);
      acc[8]  = fmaf(hk, w2r[8],  acc[8]);  acc[9]  = fmaf(hk, w2r[9],  acc[9]);
      acc[10] = fmaf(hk, w2r[10], acc[10]); acc[11] = fmaf(hk, w2r[11], acc[11]);
      acc[12] = fmaf(hk, w2r[12], acc[12]); acc[13] = fmaf(hk, w2r[13], acc[13]);
      acc[14] = fmaf(hk, w2r[14], acc[14]); acc[15] = fmaf(hk, w2r[15], acc[15]);
    }
    // finalize: x f_y x fac -> transpose buffer [edge-lane][17]
    {
      const float4 r4a = *(const float4*)&rnp[c * 16 + 0];
      const float4 r4b = *(const float4*)&rnp[c * 16 + 4];
      const float4 r4c = *(const float4*)&rnp[c * 16 + 8];
      const float4 r4d = *(const float4*)&rnp[c * 16 + 12];
      float* row = &cbuf[lane * 17];
      row[0]  = acc[0]  * r4a.x * fac; row[1]  = acc[1]  * r4a.y * fac;
      row[2]  = acc[2]  * r4a.z * fac; row[3]  = acc[3]  * r4a.w * fac;
      row[4]  = acc[4]  * r4b.x * fac; row[5]  = acc[5]  * r4b.y * fac;
      row[6]  = acc[6]  * r4b.z * fac; row[7]  = acc[7]  * r4b.w * fac;
      row[8]  = acc[8]  * r4c.x * fac; row[9]  = acc[9]  * r4c.y * fac;
      row[10] = acc[10] * r4c.z * fac; row[11] = acc[11] * r4c.w * fac;
      row[12] = acc[12] * r4d.x * fac; row[13] = acc[13] * r4d.y * fac;
      row[14] = acc[14] * r4d.z * fac; row[15] = acc[15] * r4d.w * fac;
    }
    __syncthreads();
    // edge-reduce: pair p handles (query qh, channel c*16+cc); each of the
    // 2 lanes sums 16 edges, then combines via shfl.
    float ssum = 0.f;
#pragma unroll
    for (int t2 = 0; t2 < 16; ++t2)
      ssum += cbuf[(qh * 32 + er0 + t2) * 17 + cc];
    ssum += __shfl_xor(ssum, 1);
    if ((lane & 1) == 0) dec_lds[qh][c * 16 + cc] = ssum;
    __syncthreads();
  }

  // ==== projection MLP: lane owns PH channels e32*8 .. e32*8+7 =============
  float ph[8];
  {
    const float4 ba = *(const float4*)&b_p0[e32 * 8];
    const float4 bc = *(const float4*)&b_p0[e32 * 8 + 4];
    ph[0] = ba.x; ph[1] = ba.y; ph[2] = ba.z; ph[3] = ba.w;
    ph[4] = bc.x; ph[5] = bc.y; ph[6] = bc.z; ph[7] = bc.w;
  }
#pragma unroll 2
  for (int i = 0; i < 64; ++i) {
    const float di = dec_lds[sub][i];             // LDS broadcast per half
    const float4 wa = *(const float4*)&w_p0[i * 256 + e32 * 8];
    const float4 wb = *(const float4*)&w_p0[i * 256 + e32 * 8 + 4];
    ph[0] = fmaf(di, wa.x, ph[0]); ph[1] = fmaf(di, wa.y, ph[1]);
    ph[2] = fmaf(di, wa.z, ph[2]); ph[3] = fmaf(di, wa.w, ph[3]);
    ph[4] = fmaf(di, wb.x, ph[4]); ph[5] = fmaf(di, wb.y, ph[5]);
    ph[6] = fmaf(di, wb.z, ph[6]); ph[7] = fmaf(di, wb.w, ph[7]);
  }

  float o0 = 0.f, o1 = 0.f, o2 = 0.f;
#pragma unroll
  for (int k = 0; k < 8; ++k) {
    const float gk = gelu_exact(ph[k]);
    const int row = e32 * 8 + k;
    o0 = fmaf(gk, w_p1[row * 3 + 0], o0);
    o1 = fmaf(gk, w_p1[row * 3 + 1], o1);
    o2 = fmaf(gk, w_p1[row * 3 + 2], o2);
  }
#pragma unroll
  for (int off = 1; off < 32; off <<= 1) {
    o0 += __shfl_xor(o0, off);
    o1 += __shfl_xor(o1, off);
    o2 += __shfl_xor(o2, off);
  }
  if (e32 == 0) {
    out[(size_t)gq * 3 + 0] = o0 + b_p1[0];
    out[(size_t)gq * 3 + 1] = o1 + b_p1[1];
    out[(size_t)gq * 3 + 2] = o2 + b_p1[2];
  }
}

extern "C" void kernel_launch(void* const* d_in, const int* in_sizes, int n_in,
                              void* d_out, int out_size, void* d_ws, size_t ws_size,
                              hipStream_t stream) {
  const float* lat   = (const float*)d_in[0];
  const float* rn    = (const float*)d_in[1];
  const float* qc    = (const float*)d_in[2];
  const float* w_e0  = (const float*)d_in[3];
  const float* b_e0  = (const float*)d_in[4];
  const float* w_e1  = (const float*)d_in[5];
  const float* b_e1  = (const float*)d_in[6];
  const float* w_e2  = (const float*)d_in[7];
  const float* b_e2  = (const float*)d_in[8];
  const float* w_sw0 = (const float*)d_in[9];
  const float* b_sw0 = (const float*)d_in[10];
  const float* w_sw1 = (const float*)d_in[11];
  const float* b_sw1 = (const float*)d_in[12];
  const float* w_p0  = (const float*)d_in[13];
  const float* b_p0  = (const float*)d_in[14];
  const float* w_p1  = (const float*)d_in[15];
  const float* b_p1  = (const float*)d_in[16];

  float* out = (float*)d_out;

  hipLaunchKernelGGL(magno_fused, dim3(NQ_TOT / 2), dim3(64), 0, stream,
                     lat, rn, qc, w_e0, b_e0, w_e1, b_e1, w_e2, b_e2,
                     w_sw0, b_sw0, w_sw1, b_sw1, w_p0, b_p0, w_p1, b_p1, out);
}

// Round 6
// 747.452 us; speedup vs baseline: 2.7727x; 1.9471x over previous
//
#include <hip/hip_runtime.h>
#include <math.h>

// MAGNO decoder, MI355X — round 6: instruction diet.
//   B=2, NL=2048, NQ=16384, CD=2, CIN=H=64, PH=256, COUT=3, K=32, scales {1,2}.
//
// Round-5 post-mortem: VALU-issue-bound (76% busy), ~20.7K instr/lane:
// ~45% FMA, ~30% ocml erff (~45 ops x 136 gelu), ~25% rest; 24% idle at
// 1.75 waves/SIMD. Round-6 changes:
//  * v_pk_fma_f32 via float ext_vector(2) + __builtin_elementwise_fma:
//    2 fp32 MACs / VALU instr on all four matvec loops (L0/L1/L2/proj).
//  * gelu via branchless A&S 7.1.26 erf (|err|<=1.5e-7, ~17 ops vs ~45).
//  * cbuf LDS transpose-reduce -> 5-step halving shuffle butterfly
//    (ds_swizzle pipe, not VALU); layer 2 in 2 chunks of 32 channels.
//    LDS 22.0 -> 17.4 KB => 9 blocks/CU (2.25 waves/SIMD).
// Invariant machinery (verified rounds 3-5): lane=edge, wave-uniform weight
// s_load streaming, h2 in LDS as per-lane indexed register file (each lane
// only touches its own column), d2 via __fmul_rn/__fadd_rn (bit-exact
// radius/top-k boundary decisions), (d2,pos) lexicographic top-32 ==
// jax.lax.top_k stable set, fused projection MLP.

#define NLAT 2048
#define NQ_TOT 32768   // B * NQ
#define KNB 32
#define CAP 512        // per-query candidate cap (overlaid in `big`)

typedef float f32x2 __attribute__((ext_vector_type(2)));

__device__ __forceinline__ f32x2 pk_fma(f32x2 a, f32x2 b, f32x2 c) {
  return __builtin_elementwise_fma(a, b, c);
}

__device__ __forceinline__ float gelu_fast(float x) {
  // 0.5*x*(1+erf(x/sqrt2)); erf via Abramowitz-Stegun 7.1.26, branchless.
  // |erf err| <= 1.5e-7 abs => gelu err <= ~8e-7 for |x|<=10. rcp ~1 ulp.
  const float z  = fabsf(x) * 0.70710678118654752440f;
  const float t  = __builtin_amdgcn_rcpf(fmaf(0.3275911f, z, 1.0f));
  const float p  = t * fmaf(t, fmaf(t, fmaf(t, fmaf(t, 1.061405429f,
                                                    -1.453152027f),
                                            1.421413741f),
                                    -0.284496736f),
                            0.254829592f);
  const float ex = exp2f(z * z * -1.4426950408889634f);   // exp(-z^2)
  const float er = copysignf(fmaf(-p, ex, 1.0f), x);       // erf(x/sqrt2)
  return 0.5f * x * (1.0f + er);
}

__global__ __launch_bounds__(64, 2) __attribute__((amdgpu_waves_per_eu(2, 4)))
void magno_fused(const float* __restrict__ lat,   // [NL,2]
                 const float* __restrict__ rn,    // [B,NL,64]
                 const float* __restrict__ qc,    // [B*NQ,2]
                 const float* __restrict__ w_e0, const float* __restrict__ b_e0,
                 const float* __restrict__ w_e1, const float* __restrict__ b_e1,
                 const float* __restrict__ w_e2, const float* __restrict__ b_e2,
                 const float* __restrict__ w_sw0, const float* __restrict__ b_sw0,
                 const float* __restrict__ w_sw1, const float* __restrict__ b_sw1,
                 const float* __restrict__ w_p0, const float* __restrict__ b_p0,
                 const float* __restrict__ w_p1, const float* __restrict__ b_p1,
                 float* __restrict__ out)         // [B*NQ,3]
{
  const float r1sq = (float)(0.055 * 0.055);
  const float r2sq = (float)((0.055 * 2.0) * (0.055 * 2.0));

  // big: phase 1 = candidates [cd2 q0 | cidx q0 | cd2 q1 | cidx q1] (4*512)
  //      phase 2 = h2[64 k][64 lane] (per-lane private column)
  __shared__ float big[4096];                     // 16 KB
  __shared__ float sd2[2][KNB];
  __shared__ int   sidx[2][KNB];
  __shared__ float dec_lds[2][64];

  const int lane = threadIdx.x;
  const int sub  = lane >> 5;                     // wave's query 0/1
  const int e32  = lane & 31;                     // edge slot within query

  // ==== phase 1a: distance pass + compaction (full wave, per query) ========
  int nc0 = 0, nc1 = 0;
#pragma unroll
  for (int s = 0; s < 2; ++s) {
    float* cds = big + s * 2 * CAP;
    int*   cis = (int*)(big + CAP + s * 2 * CAP);
    const int gqs = blockIdx.x * 2 + s;
    const float2 qs = *(const float2*)&qc[2 * gqs];
    int nc = 0;
    for (int t = 0; t < NLAT; t += 64) {
      const int l = t + lane;
      const float2 yv = *(const float2*)&lat[2 * l];
      const float dx = qs.x - yv.x, dy = qs.y - yv.y;
      const float d2 = __fadd_rn(__fmul_rn(dx, dx), __fmul_rn(dy, dy));
      const bool hit = d2 <= r2sq;
      const unsigned long long m = __ballot(hit);
      if (hit) {
        const int pos = nc + __popcll(m & (((unsigned long long)1 << lane) - 1ull));
        if (pos < CAP) { cds[pos] = d2; cis[pos] = l; }
      }
      nc += (int)__popcll(m);
    }
    if (nc > CAP) nc = CAP;    // mean ~78; unreachable
    if (s == 0) nc0 = nc; else nc1 = nc;
  }
  __syncthreads();

  // ==== phase 1b: top-32 by (d2,pos), both queries in half-wave parallel ===
  const int ncH = sub ? nc1 : nc0;
  float* cdH = big + sub * 2 * CAP;
  int*   ciH = (int*)(big + CAP + sub * 2 * CAP);

  if (ncH <= KNB) {
    if (e32 < ncH) { sd2[sub][e32] = cdH[e32]; sidx[sub][e32] = ciH[e32]; }
  }
  __syncthreads();
  if (nc0 > KNB || nc1 > KNB) {                   // wave-uniform condition
    const bool ext = ncH > KNB;
    for (int r = 0; r < KNB; ++r) {
      unsigned long long best = ~0ull;
      if (ext) {
        for (int t = e32; t < ncH; t += 32) {
          const unsigned long long key =
              ((unsigned long long)__float_as_uint(cdH[t]) << 32) | (unsigned)t;
          if (key < best) best = key;
        }
      }
#pragma unroll
      for (int off = 16; off > 0; off >>= 1) {    // butterfly within half-wave
        const unsigned long long o = __shfl_xor(best, off);
        if (o < best) best = o;
      }
      if (ext && e32 == 0) {
        const int pos = (int)(best & 0xffffffffu);
        sd2[sub][r]  = __uint_as_float((unsigned)(best >> 32));
        sidx[sub][r] = ciH[pos];
        cdH[pos] = __uint_as_float(0x7f800000u);  // +inf: claimed
      }
      __syncthreads();
    }
  }
  const int n_sel = ncH < KNB ? ncH : KNB;

  // ==== phase 2: lane = edge ===============================================
  const int gq = blockIdx.x * 2 + sub;
  const int bb = gq >> 14;                        // batch = gq / NQ
  const float2 qv = *(const float2*)&qc[2 * gq];

  const bool  active = e32 < n_sel;
  const float d2e = active ? sd2[sub][e32] : 1e30f;
  const int   ie  = active ? sidx[sub][e32] : 0;
  const float2 yv = *(const float2*)&lat[2 * ie];
  __syncthreads();                                // candidate reads done

  // layer 0: h1 in registers; packed 2-channels-at-a-time
  float h1[64];
  {
    const f32x2 yx2 = {yv.x, yv.x}, yy2 = {yv.y, yv.y};
    const f32x2 qx2 = {qv.x, qv.x}, qy2 = {qv.y, qv.y};
#pragma unroll
    for (int i = 0; i < 64; i += 2) {
      const f32x2 w0 = *(const f32x2*)&w_e0[i];
      const f32x2 w1 = *(const f32x2*)&w_e0[64 + i];
      const f32x2 w2 = *(const f32x2*)&w_e0[128 + i];
      const f32x2 w3 = *(const f32x2*)&w_e0[192 + i];
      const f32x2 b0 = *(const f32x2*)&b_e0[i];
      const f32x2 t = pk_fma(yx2, w0, pk_fma(yy2, w1,
                      pk_fma(qx2, w2, pk_fma(qy2, w3, b0))));
      h1[i]     = gelu_fast(t.x);
      h1[i + 1] = gelu_fast(t.y);
    }
  }

  // layer 1: 4 groups of 16 channels; only L[8] (f32x2) live; h2 -> LDS
  for (int g = 0; g < 4; ++g) {
    f32x2 L[8];
#pragma unroll
    for (int k = 0; k < 8; ++k) L[k] = *(const f32x2*)&b_e1[g * 16 + 2 * k];
#pragma unroll
    for (int i = 0; i < 64; ++i) {
      const float hi = h1[i];
      const f32x2 hi2 = {hi, hi};
      const f32x2* wr = (const f32x2*)&w_e1[i * 64 + g * 16];
      L[0] = pk_fma(hi2, wr[0], L[0]); L[1] = pk_fma(hi2, wr[1], L[1]);
      L[2] = pk_fma(hi2, wr[2], L[2]); L[3] = pk_fma(hi2, wr[3], L[3]);
      L[4] = pk_fma(hi2, wr[4], L[4]); L[5] = pk_fma(hi2, wr[5], L[5]);
      L[6] = pk_fma(hi2, wr[6], L[6]); L[7] = pk_fma(hi2, wr[7], L[7]);
    }
#pragma unroll
    for (int k = 0; k < 8; ++k) {
      big[(g * 16 + 2 * k    ) * 64 + lane] = gelu_fast(L[k].x);
      big[(g * 16 + 2 * k + 1) * 64 + lane] = gelu_fast(L[k].y);
    }
  }

  // scale-mix softmax + per-edge factor
  float z0 = b_sw1[0], z1 = b_sw1[1];
#pragma unroll
  for (int k = 0; k < 16; ++k) {
    float t = fmaf(qv.x, w_sw0[k], fmaf(qv.y, w_sw0[16 + k], b_sw0[k]));
    t = fmaxf(t, 0.f);
    z0 = fmaf(t, w_sw1[2 * k + 0], z0);
    z1 = fmaf(t, w_sw1[2 * k + 1], z1);
  }
  const float mz = fmaxf(z0, z1);
  const float ex0 = expf(z0 - mz), ex1 = expf(z1 - mz);
  const float inv = 1.f / (ex0 + ex1);
  const float sw0 = ex0 * inv, sw1 = ex1 * inv;   // sw0<->scale1, sw1<->scale2

  const bool v1 = active && (d2e <= r1sq);
  const unsigned long long mB = __ballot(v1);
  const int cnt1 = (int)__popcll((mB >> (lane & 32)) & 0xffffffffull);
  float fac = 0.f;
  if (active) {
    fac = sw1 / (float)n_sel;
    if (v1) fac += sw0 / (float)cnt1;
  }
  const f32x2 fac2 = {fac, fac};

  // layer 2: 2 chunks of 32 output channels; finalize + shuffle-reduce.
  // big[k*64+lane] is this lane's private h2 column (same-lane RAW only).
  const float* rnp = rn + ((size_t)bb * NLAT + ie) * 64;

  for (int c = 0; c < 2; ++c) {
    f32x2 A[16];
#pragma unroll
    for (int j = 0; j < 16; ++j) A[j] = *(const f32x2*)&b_e2[c * 32 + 2 * j];
#pragma unroll
    for (int k = 0; k < 64; ++k) {
      const float hk = big[k * 64 + lane];
      const f32x2 hk2 = {hk, hk};
      const f32x2* w2r = (const f32x2*)&w_e2[k * 64 + c * 32];
      A[0]  = pk_fma(hk2, w2r[0],  A[0]);  A[1]  = pk_fma(hk2, w2r[1],  A[1]);
      A[2]  = pk_fma(hk2, w2r[2],  A[2]);  A[3]  = pk_fma(hk2, w2r[3],  A[3]);
      A[4]  = pk_fma(hk2, w2r[4],  A[4]);  A[5]  = pk_fma(hk2, w2r[5],  A[5]);
      A[6]  = pk_fma(hk2, w2r[6],  A[6]);  A[7]  = pk_fma(hk2, w2r[7],  A[7]);
      A[8]  = pk_fma(hk2, w2r[8],  A[8]);  A[9]  = pk_fma(hk2, w2r[9],  A[9]);
      A[10] = pk_fma(hk2, w2r[10], A[10]); A[11] = pk_fma(hk2, w2r[11], A[11]);
      A[12] = pk_fma(hk2, w2r[12], A[12]); A[13] = pk_fma(hk2, w2r[13], A[13]);
      A[14] = pk_fma(hk2, w2r[14], A[14]); A[15] = pk_fma(hk2, w2r[15], A[15]);
    }

    // finalize contrib = h3 * f_y * fac
    float v[32];
#pragma unroll
    for (int j = 0; j < 8; ++j) {
      const float4 r4 = *(const float4*)&rnp[c * 32 + 4 * j];
      f32x2 m0 = A[2 * j]     * (f32x2){r4.x, r4.y} * fac2;
      f32x2 m1 = A[2 * j + 1] * (f32x2){r4.z, r4.w} * fac2;
      v[4 * j + 0] = m0.x; v[4 * j + 1] = m0.y;
      v[4 * j + 2] = m1.x; v[4 * j + 3] = m1.y;
    }

    // halving butterfly reduce: 32 ch over 32 lanes (within half-wave).
    // step t: keep half chosen by bit t of e32; exchange the other half.
    float w16[16];
    { const bool up = (e32 & 1);
#pragma unroll
      for (int k = 0; k < 16; ++k) {
        const float keep = up ? v[16 + k] : v[k];
        const float send = up ? v[k] : v[16 + k];
        w16[k] = keep + __shfl_xor(send, 1);
      } }
    float w8[8];
    { const bool up = (e32 & 2);
#pragma unroll
      for (int k = 0; k < 8; ++k) {
        const float keep = up ? w16[8 + k] : w16[k];
        const float send = up ? w16[k] : w16[8 + k];
        w8[k] = keep + __shfl_xor(send, 2);
      } }
    float w4[4];
    { const bool up = (e32 & 4);
#pragma unroll
      for (int k = 0; k < 4; ++k) {
        const float keep = up ? w8[4 + k] : w8[k];
        const float send = up ? w8[k] : w8[4 + k];
        w4[k] = keep + __shfl_xor(send, 4);
      } }
    float w2[2];
    { const bool up = (e32 & 8);
#pragma unroll
      for (int k = 0; k < 2; ++k) {
        const float keep = up ? w4[2 + k] : w4[k];
        const float send = up ? w4[k] : w4[2 + k];
        w2[k] = keep + __shfl_xor(send, 8);
      } }
    float w1;
    { const bool up = (e32 & 16);
      const float keep = up ? w2[1] : w2[0];
      const float send = up ? w2[0] : w2[1];
      w1 = keep + __shfl_xor(send, 16); }

    // lane owns channel bitrev5(e32) of this chunk (bijection on 0..31)
    const int cl = ((e32 & 1) << 4) | ((e32 & 2) << 2) | (e32 & 4) |
                   ((e32 & 8) >> 2) | ((e32 & 16) >> 4);
    dec_lds[sub][c * 32 + cl] = w1;
  }
  __syncthreads();                                // dec_lds cross-lane reads

  // ==== projection MLP: lane owns PH channels e32*8 .. e32*8+7 =============
  f32x2 ph2[4];
  {
    const float4 ba = *(const float4*)&b_p0[e32 * 8];
    const float4 bc = *(const float4*)&b_p0[e32 * 8 + 4];
    ph2[0] = (f32x2){ba.x, ba.y}; ph2[1] = (f32x2){ba.z, ba.w};
    ph2[2] = (f32x2){bc.x, bc.y}; ph2[3] = (f32x2){bc.z, bc.w};
  }
#pragma unroll 4
  for (int i = 0; i < 64; ++i) {
    const float di = dec_lds[sub][i];             // LDS broadcast per half
    const f32x2 di2 = {di, di};
    const float4 wa = *(const float4*)&w_p0[i * 256 + e32 * 8];
    const float4 wb = *(const float4*)&w_p0[i * 256 + e32 * 8 + 4];
    ph2[0] = pk_fma(di2, (f32x2){wa.x, wa.y}, ph2[0]);
    ph2[1] = pk_fma(di2, (f32x2){wa.z, wa.w}, ph2[1]);
    ph2[2] = pk_fma(di2, (f32x2){wb.x, wb.y}, ph2[2]);
    ph2[3] = pk_fma(di2, (f32x2){wb.z, wb.w}, ph2[3]);
  }

  float o0 = 0.f, o1 = 0.f, o2 = 0.f;
#pragma unroll
  for (int k = 0; k < 8; ++k) {
    const float pv = (k & 1) ? ph2[k >> 1].y : ph2[k >> 1].x;  // static after unroll
    const float gk = gelu_fast(pv);
    const int row = e32 * 8 + k;
    o0 = fmaf(gk, w_p1[row * 3 + 0], o0);
    o1 = fmaf(gk, w_p1[row * 3 + 1], o1);
    o2 = fmaf(gk, w_p1[row * 3 + 2], o2);
  }
#pragma unroll
  for (int off = 1; off < 32; off <<= 1) {
    o0 += __shfl_xor(o0, off);
    o1 += __shfl_xor(o1, off);
    o2 += __shfl_xor(o2, off);
  }
  if (e32 == 0) {
    out[(size_t)gq * 3 + 0] = o0 + b_p1[0];
    out[(size_t)gq * 3 + 1] = o1 + b_p1[1];
    out[(size_t)gq * 3 + 2] = o2 + b_p1[2];
  }
}

extern "C" void kernel_launch(void* const* d_in, const int* in_sizes, int n_in,
                              void* d_out, int out_size, void* d_ws, size_t ws_size,
                              hipStream_t stream) {
  const float* lat   = (const float*)d_in[0];
  const float* rn    = (const float*)d_in[1];
  const float* qc    = (const float*)d_in[2];
  const float* w_e0  = (const float*)d_in[3];
  const float* b_e0  = (const float*)d_in[4];
  const float* w_e1  = (const float*)d_in[5];
  const float* b_e1  = (const float*)d_in[6];
  const float* w_e2  = (const float*)d_in[7];
  const float* b_e2  = (const float*)d_in[8];
  const float* w_sw0 = (const float*)d_in[9];
  const float* b_sw0 = (const float*)d_in[10];
  const float* w_sw1 = (const float*)d_in[11];
  const float* b_sw1 = (const float*)d_in[12];
  const float* w_p0  = (const float*)d_in[13];
  const float* b_p0  = (const float*)d_in[14];
  const float* w_p1  = (const float*)d_in[15];
  const float* b_p1  = (const float*)d_in[16];

  float* out = (float*)d_out;

  hipLaunchKernelGGL(magno_fused, dim3(NQ_TOT / 2), dim3(64), 0, stream,
                     lat, rn, qc, w_e0, b_e0, w_e1, b_e1, w_e2, b_e2,
                     w_sw0, b_sw0, w_sw1, b_sw1, w_p0, b_p0, w_p1, b_p1, out);
}

// Round 7
// 543.359 us; speedup vs baseline: 3.8141x; 1.3756x over previous
//
#include <hip/hip_runtime.h>
#include <math.h>

// MAGNO decoder, MI355X — round 7: occupancy via LDS diet + h1 recompute.
//   B=2, NL=2048, NQ=16384, CD=2, CIN=H=64, PH=256, COUT=3, K=32, scales {1,2}.
//
// Round-6 post-mortem: latency-bound (VALUBusy 41% CU-level ~ 12%/SIMD issue,
// occupancy 2.25 waves/SIMD, s_load weight-stream stalls). This round deletes
// the 16KB h2 LDS buffer that capped occupancy:
//  * A[32 f32x2] = all 64 layer-2 accumulators stay in VGPRs (64 regs).
//  * h2 produced in 2 groups of 32 channels; h1 recomputed per group
//    (layer0 = 2 pk_fma + gelu per pair; query-part u precomputed into a
//    512B LDS broadcast table). h1/h2 never materialize anywhere.
//  * LDS 17.4KB -> ~5KB (candidates 224/query + u + dec + sel) =>
//    occupancy becomes VGPR-bound (~4 waves/SIMD at <=128 VGPR).
// Invariant machinery (verified r3-r6): lane=edge, wave-uniform weight s_load
// streaming, pk_fma everywhere, fast branchless gelu (r6-verified), d2 via
// __fmul_rn/__fadd_rn (bit-exact radius/top-k decisions), (d2,pos)
// lexicographic top-32 == jax.lax.top_k stable set, halving butterfly
// edge-reduce, fused projection MLP.

#define NLAT 2048
#define NQ_TOT 32768   // B * NQ
#define KNB 32
#define CAP 224        // per-query candidate cap; mean ~78, ~17 sigma headroom

typedef float f32x2 __attribute__((ext_vector_type(2)));

__device__ __forceinline__ f32x2 pk_fma(f32x2 a, f32x2 b, f32x2 c) {
  return __builtin_elementwise_fma(a, b, c);
}

__device__ __forceinline__ float gelu_fast(float x) {
  // 0.5*x*(1+erf(x/sqrt2)); erf via Abramowitz-Stegun 7.1.26, branchless.
  // |erf err| <= 1.5e-7 abs => gelu err <= ~8e-7 for |x|<=10.
  const float z  = fabsf(x) * 0.70710678118654752440f;
  const float t  = __builtin_amdgcn_rcpf(fmaf(0.3275911f, z, 1.0f));
  const float p  = t * fmaf(t, fmaf(t, fmaf(t, fmaf(t, 1.061405429f,
                                                    -1.453152027f),
                                            1.421413741f),
                                    -0.284496736f),
                            0.254829592f);
  const float ex = exp2f(z * z * -1.4426950408889634f);   // exp(-z^2)
  const float er = copysignf(fmaf(-p, ex, 1.0f), x);       // erf(x/sqrt2)
  return 0.5f * x * (1.0f + er);
}

__global__ __launch_bounds__(64, 2) __attribute__((amdgpu_waves_per_eu(2, 4)))
void magno_fused(const float* __restrict__ lat,   // [NL,2]
                 const float* __restrict__ rn,    // [B,NL,64]
                 const float* __restrict__ qc,    // [B*NQ,2]
                 const float* __restrict__ w_e0, const float* __restrict__ b_e0,
                 const float* __restrict__ w_e1, const float* __restrict__ b_e1,
                 const float* __restrict__ w_e2, const float* __restrict__ b_e2,
                 const float* __restrict__ w_sw0, const float* __restrict__ b_sw0,
                 const float* __restrict__ w_sw1, const float* __restrict__ b_sw1,
                 const float* __restrict__ w_p0, const float* __restrict__ b_p0,
                 const float* __restrict__ w_p1, const float* __restrict__ b_p1,
                 float* __restrict__ out)         // [B*NQ,3]
{
  const float r1sq = (float)(0.055 * 0.055);
  const float r2sq = (float)((0.055 * 2.0) * (0.055 * 2.0));

  __shared__ float cd2s[2][CAP];                  // 1.75 KB
  __shared__ int   cidxs[2][CAP];                 // 1.75 KB
  __shared__ float sd2[2][KNB];
  __shared__ int   sidx[2][KNB];
  __shared__ float u_lds[2][64];                  // query-part of layer 0
  __shared__ float dec_lds[2][64];

  const int lane = threadIdx.x;
  const int sub  = lane >> 5;                     // wave's query 0/1
  const int e32  = lane & 31;                     // edge slot within query

  // ==== phase 1a: distance pass + compaction (full wave, per query) ========
  int nc0 = 0, nc1 = 0;
#pragma unroll
  for (int s = 0; s < 2; ++s) {
    float* cds = cd2s[s];
    int*   cis = cidxs[s];
    const int gqs = blockIdx.x * 2 + s;
    const float2 qs = *(const float2*)&qc[2 * gqs];
    int nc = 0;
    for (int t = 0; t < NLAT; t += 64) {
      const int l = t + lane;
      const float2 yv = *(const float2*)&lat[2 * l];
      const float dx = qs.x - yv.x, dy = qs.y - yv.y;
      const float d2 = __fadd_rn(__fmul_rn(dx, dx), __fmul_rn(dy, dy));
      const bool hit = d2 <= r2sq;
      const unsigned long long m = __ballot(hit);
      if (hit) {
        const int pos = nc + __popcll(m & (((unsigned long long)1 << lane) - 1ull));
        if (pos < CAP) { cds[pos] = d2; cis[pos] = l; }
      }
      nc += (int)__popcll(m);
    }
    if (nc > CAP) nc = CAP;    // mean ~78; unreachable
    if (s == 0) nc0 = nc; else nc1 = nc;
  }
  __syncthreads();

  // ==== phase 1b: top-32 by (d2,pos), both queries in half-wave parallel ===
  const int ncH = sub ? nc1 : nc0;
  float* cdH = cd2s[sub];
  int*   ciH = cidxs[sub];

  if (ncH <= KNB) {
    if (e32 < ncH) { sd2[sub][e32] = cdH[e32]; sidx[sub][e32] = ciH[e32]; }
  }
  __syncthreads();
  if (nc0 > KNB || nc1 > KNB) {                   // wave-uniform condition
    const bool ext = ncH > KNB;
    for (int r = 0; r < KNB; ++r) {
      unsigned long long best = ~0ull;
      if (ext) {
        for (int t = e32; t < ncH; t += 32) {
          const unsigned long long key =
              ((unsigned long long)__float_as_uint(cdH[t]) << 32) | (unsigned)t;
          if (key < best) best = key;
        }
      }
#pragma unroll
      for (int off = 16; off > 0; off >>= 1) {    // butterfly within half-wave
        const unsigned long long o = __shfl_xor(best, off);
        if (o < best) best = o;
      }
      if (ext && e32 == 0) {
        const int pos = (int)(best & 0xffffffffu);
        sd2[sub][r]  = __uint_as_float((unsigned)(best >> 32));
        sidx[sub][r] = ciH[pos];
        cdH[pos] = __uint_as_float(0x7f800000u);  // +inf: claimed
      }
      __syncthreads();
    }
  }
  const int n_sel = ncH < KNB ? ncH : KNB;

  // ==== phase 2 setup: lane = edge =========================================
  const int gq = blockIdx.x * 2 + sub;
  const int bb = gq >> 14;                        // batch = gq / NQ
  const float2 qv = *(const float2*)&qc[2 * gq];

  const bool  active = e32 < n_sel;
  const float d2e = active ? sd2[sub][e32] : 1e30f;
  const int   ie  = active ? sidx[sub][e32] : 0;
  const float2 yv = *(const float2*)&lat[2 * ie];

  // u table: u_i = qx*w_e0[128+i] + qy*w_e0[192+i] + b_e0[i] (per query).
  // lane (sub,e32) computes channels 2*e32, 2*e32+1 of its query.
  {
    const f32x2 w2p = *(const f32x2*)&w_e0[128 + 2 * e32];
    const f32x2 w3p = *(const f32x2*)&w_e0[192 + 2 * e32];
    const f32x2 bp  = *(const f32x2*)&b_e0[2 * e32];
    const f32x2 qx2 = {qv.x, qv.x}, qy2 = {qv.y, qv.y};
    const f32x2 u2 = pk_fma(qx2, w2p, pk_fma(qy2, w3p, bp));
    *(f32x2*)&u_lds[sub][2 * e32] = u2;
  }
  __syncthreads();

  // ==== phase 2: edge MLP, h1 recomputed per group, A resident =============
  float A_[64];                                   // layer-2 accumulators
  f32x2* A = (f32x2*)A_;
#pragma unroll
  for (int j = 0; j < 32; ++j) A[j] = *(const f32x2*)&b_e2[2 * j];

  const f32x2 yx2 = {yv.x, yv.x}, yy2 = {yv.y, yv.y};

#pragma unroll 1
  for (int g = 0; g < 2; ++g) {                   // 2 groups of 32 h2 channels
    f32x2 L[16];
#pragma unroll
    for (int k = 0; k < 16; ++k) L[k] = *(const f32x2*)&b_e1[g * 32 + 2 * k];

    // layer 1 for this group; h1 recomputed pairwise (u from LDS broadcast)
#pragma unroll 4
    for (int i = 0; i < 64; i += 2) {
      const f32x2 w0p = *(const f32x2*)&w_e0[i];        // s_load (uniform)
      const f32x2 w1p = *(const f32x2*)&w_e0[64 + i];
      const f32x2 u2  = *(const f32x2*)&u_lds[sub][i];  // ds broadcast
      const f32x2 t2  = pk_fma(yx2, w0p, pk_fma(yy2, w1p, u2));
      const float ha = gelu_fast(t2.x);
      const float hb = gelu_fast(t2.y);
      const f32x2 ha2 = {ha, ha}, hb2 = {hb, hb};
      const f32x2* wrA = (const f32x2*)&w_e1[i * 64 + g * 32];
      const f32x2* wrB = (const f32x2*)&w_e1[(i + 1) * 64 + g * 32];
#pragma unroll
      for (int k = 0; k < 16; ++k) L[k] = pk_fma(ha2, wrA[k], L[k]);
#pragma unroll
      for (int k = 0; k < 16; ++k) L[k] = pk_fma(hb2, wrB[k], L[k]);
    }

    // layer 2: consume this group's 32 h2 channels immediately
#pragma unroll
    for (int kk = 0; kk < 32; ++kk) {
      const float h2v = gelu_fast((kk & 1) ? L[kk >> 1].y : L[kk >> 1].x);
      const f32x2 h2 = {h2v, h2v};
      const f32x2* w2r = (const f32x2*)&w_e2[(g * 32 + kk) * 64];
#pragma unroll
      for (int j = 0; j < 32; ++j) A[j] = pk_fma(h2, w2r[j], A[j]);
    }
  }

  // ==== phase 3: scale-mix softmax + per-edge factor ========================
  float z0 = b_sw1[0], z1 = b_sw1[1];
#pragma unroll
  for (int k = 0; k < 16; ++k) {
    float t = fmaf(qv.x, w_sw0[k], fmaf(qv.y, w_sw0[16 + k], b_sw0[k]));
    t = fmaxf(t, 0.f);
    z0 = fmaf(t, w_sw1[2 * k + 0], z0);
    z1 = fmaf(t, w_sw1[2 * k + 1], z1);
  }
  const float mz = fmaxf(z0, z1);
  const float ex0 = expf(z0 - mz), ex1 = expf(z1 - mz);
  const float inv = 1.f / (ex0 + ex1);
  const float sw0 = ex0 * inv, sw1 = ex1 * inv;   // sw0<->scale1, sw1<->scale2

  const bool v1 = active && (d2e <= r1sq);
  const unsigned long long mB = __ballot(v1);
  const int cnt1 = (int)__popcll((mB >> (lane & 32)) & 0xffffffffull);
  float fac = 0.f;
  if (active) {
    fac = sw1 / (float)n_sel;
    if (v1) fac += sw0 / (float)cnt1;
  }
  const f32x2 fac2 = {fac, fac};

  // ==== phase 4: finalize + halving butterfly edge-reduce ===================
  const float* rnp = rn + ((size_t)bb * NLAT + ie) * 64;

#pragma unroll
  for (int c = 0; c < 2; ++c) {                   // 2 chunks of 32 channels
    float v[32];
#pragma unroll
    for (int j = 0; j < 8; ++j) {
      const float4 r4 = *(const float4*)&rnp[c * 32 + 4 * j];
      f32x2 m0 = A[c * 16 + 2 * j]     * (f32x2){r4.x, r4.y} * fac2;
      f32x2 m1 = A[c * 16 + 2 * j + 1] * (f32x2){r4.z, r4.w} * fac2;
      v[4 * j + 0] = m0.x; v[4 * j + 1] = m0.y;
      v[4 * j + 2] = m1.x; v[4 * j + 3] = m1.y;
    }

    float w16[16];
    { const bool up = (e32 & 1);
#pragma unroll
      for (int k = 0; k < 16; ++k) {
        const float keep = up ? v[16 + k] : v[k];
        const float send = up ? v[k] : v[16 + k];
        w16[k] = keep + __shfl_xor(send, 1);
      } }
    float w8[8];
    { const bool up = (e32 & 2);
#pragma unroll
      for (int k = 0; k < 8; ++k) {
        const float keep = up ? w16[8 + k] : w16[k];
        const float send = up ? w16[k] : w16[8 + k];
        w8[k] = keep + __shfl_xor(send, 2);
      } }
    float w4[4];
    { const bool up = (e32 & 4);
#pragma unroll
      for (int k = 0; k < 4; ++k) {
        const float keep = up ? w8[4 + k] : w8[k];
        const float send = up ? w8[k] : w8[4 + k];
        w4[k] = keep + __shfl_xor(send, 4);
      } }
    float w2[2];
    { const bool up = (e32 & 8);
#pragma unroll
      for (int k = 0; k < 2; ++k) {
        const float keep = up ? w4[2 + k] : w4[k];
        const float send = up ? w4[k] : w4[2 + k];
        w2[k] = keep + __shfl_xor(send, 8);
      } }
    float w1;
    { const bool up = (e32 & 16);
      const float keep = up ? w2[1] : w2[0];
      const float send = up ? w2[0] : w2[1];
      w1 = keep + __shfl_xor(send, 16); }

    // lane owns channel bitrev5(e32) of this chunk (bijection on 0..31)
    const int cl = ((e32 & 1) << 4) | ((e32 & 2) << 2) | (e32 & 4) |
                   ((e32 & 8) >> 2) | ((e32 & 16) >> 4);
    dec_lds[sub][c * 32 + cl] = w1;
  }
  __syncthreads();                                // dec_lds cross-lane reads

  // ==== phase 5: projection MLP: lane owns PH channels e32*8 .. e32*8+7 ====
  f32x2 ph2[4];
  {
    const float4 ba = *(const float4*)&b_p0[e32 * 8];
    const float4 bc = *(const float4*)&b_p0[e32 * 8 + 4];
    ph2[0] = (f32x2){ba.x, ba.y}; ph2[1] = (f32x2){ba.z, ba.w};
    ph2[2] = (f32x2){bc.x, bc.y}; ph2[3] = (f32x2){bc.z, bc.w};
  }
#pragma unroll 4
  for (int i = 0; i < 64; ++i) {
    const float di = dec_lds[sub][i];             // LDS broadcast per half
    const f32x2 di2 = {di, di};
    const float4 wa = *(const float4*)&w_p0[i * 256 + e32 * 8];
    const float4 wb = *(const float4*)&w_p0[i * 256 + e32 * 8 + 4];
    ph2[0] = pk_fma(di2, (f32x2){wa.x, wa.y}, ph2[0]);
    ph2[1] = pk_fma(di2, (f32x2){wa.z, wa.w}, ph2[1]);
    ph2[2] = pk_fma(di2, (f32x2){wb.x, wb.y}, ph2[2]);
    ph2[3] = pk_fma(di2, (f32x2){wb.z, wb.w}, ph2[3]);
  }

  float o0 = 0.f, o1 = 0.f, o2 = 0.f;
#pragma unroll
  for (int k = 0; k < 8; ++k) {
    const float pv = (k & 1) ? ph2[k >> 1].y : ph2[k >> 1].x;
    const float gk = gelu_fast(pv);
    const int row = e32 * 8 + k;
    o0 = fmaf(gk, w_p1[row * 3 + 0], o0);
    o1 = fmaf(gk, w_p1[row * 3 + 1], o1);
    o2 = fmaf(gk, w_p1[row * 3 + 2], o2);
  }
#pragma unroll
  for (int off = 1; off < 32; off <<= 1) {
    o0 += __shfl_xor(o0, off);
    o1 += __shfl_xor(o1, off);
    o2 += __shfl_xor(o2, off);
  }
  if (e32 == 0) {
    out[(size_t)gq * 3 + 0] = o0 + b_p1[0];
    out[(size_t)gq * 3 + 1] = o1 + b_p1[1];
    out[(size_t)gq * 3 + 2] = o2 + b_p1[2];
  }
}

extern "C" void kernel_launch(void* const* d_in, const int* in_sizes, int n_in,
                              void* d_out, int out_size, void* d_ws, size_t ws_size,
                              hipStream_t stream) {
  const float* lat   = (const float*)d_in[0];
  const float* rn    = (const float*)d_in[1];
  const float* qc    = (const float*)d_in[2];
  const float* w_e0  = (const float*)d_in[3];
  const float* b_e0  = (const float*)d_in[4];
  const float* w_e1  = (const float*)d_in[5];
  const float* b_e1  = (const float*)d_in[6];
  const float* w_e2  = (const float*)d_in[7];
  const float* b_e2  = (const float*)d_in[8];
  const float* w_sw0 = (const float*)d_in[9];
  const float* b_sw0 = (const float*)d_in[10];
  const float* w_sw1 = (const float*)d_in[11];
  const float* b_sw1 = (const float*)d_in[12];
  const float* w_p0  = (const float*)d_in[13];
  const float* b_p0  = (const float*)d_in[14];
  const float* w_p1  = (const float*)d_in[15];
  const float* b_p1  = (const float*)d_in[16];

  float* out = (float*)d_out;

  hipLaunchKernelGGL(magno_fused, dim3(NQ_TOT / 2), dim3(64), 0, stream,
                     lat, rn, qc, w_e0, b_e0, w_e1, b_e1, w_e2, b_e2,
                     w_sw0, b_sw0, w_sw1, b_sw1, w_p0, b_p0, w_p1, b_p1, out);
}